// Round 1
// baseline (160.589 us; speedup 1.0000x reference)
//
#include <hip/hip_runtime.h>
#include <hip/hip_bf16.h>

// VQ-VAE vector quantizer, MI355X gfx950.
// z_e: (32, 256, 32, 32) fp32  -> N=32768 rows (b*1024 + h*32+w), D=256
// W:   (1024, 256) fp32, K=1024 codes
// out: z_q (32,256,32,32) fp32 [8388608] ++ embedding_loss ++ commitment_loss
//
// Scores via bf16 MFMA 16x16x32 (no fp32 MFMA on CDNA4): argmin_k(||w_k||^2 - 2 z.w_k).
// Losses computed from fp32 z and fp32 gathered W (exact); both scalars identical.

#define DIM      256
#define NCODES   1024
#define SPB      1024      // spatial positions per batch (32*32)
#define ZQ_ELEMS 8388608
#define BLK_ROWS 128

typedef float f32x4  __attribute__((ext_vector_type(4)));
typedef short bf16x8 __attribute__((ext_vector_type(8)));

__device__ __forceinline__ short f2bf(float f) {
    union { float f; unsigned u; } v; v.f = f;
    unsigned r = v.u + 0x7FFFu + ((v.u >> 16) & 1u);   // RNE
    return (short)(r >> 16);
}

// K1: wnorm[k] = ||w_k||^2 ; also zero the loss accumulator. One wave per code.
__global__ __launch_bounds__(64) void wnorm_kernel(const float* __restrict__ w,
                                                   float* __restrict__ wn,
                                                   float* __restrict__ acc) {
    int k = blockIdx.x;
    int l = threadIdx.x;
    const float* wr = w + (size_t)k * DIM;
    float s = 0.f;
#pragma unroll
    for (int i = 0; i < 4; ++i) { float v = wr[l + 64 * i]; s += v * v; }
#pragma unroll
    for (int off = 32; off; off >>= 1) s += __shfl_down(s, off);
    if (l == 0) wn[k] = s;
    if (k == 0 && l == 0) *acc = 0.f;
}

// K2: main fused kernel. grid 256 x 256 threads. 128 rows/block, 32 rows/wave.
__global__ __launch_bounds__(256) void vq_main(const float* __restrict__ z,
                                               const float* __restrict__ w,
                                               const float* __restrict__ wn,
                                               float* __restrict__ out,
                                               float* __restrict__ acc) {
    // W k-tile: 16 codes x 256 d bf16, padded row to 264 (16B-aligned, conflict-free b128)
    __shared__ short wb[2][16][264];
    __shared__ float wnl[NCODES];
    __shared__ int   ridx[BLK_ROWS];
    __shared__ float wsum[4];

    const int t  = threadIdx.x;
    const int wv = t >> 6;
    const int l  = t & 63;
    const int n  = l & 15;       // MFMA A-row / B-row (code) / C-col index
    const int q  = l >> 4;       // quad

    const int n0    = blockIdx.x * BLK_ROWS;
    const int batch = n0 >> 10;
    const int sbase = n0 & 1023;
    const float* zb = z + (size_t)batch * DIM * SPB + sbase;  // + c*SPB + s_local

    // stage wnorm to LDS
    for (int i = t; i < NCODES; i += 256) wnl[i] = wn[i];

    // ---- A fragments: 32 rows per wave (2 sets of 16), all 256 d, bf16 in regs ----
    // A[m=lane&15][k = quad*8 + j] per 32-d tile T.
    bf16x8 af[2][8];
#pragma unroll
    for (int sg = 0; sg < 2; ++sg) {
        const float* zr = zb + (32 * wv + 16 * sg + n);
#pragma unroll
        for (int T = 0; T < 8; ++T) {
            bf16x8 a;
#pragma unroll
            for (int j = 0; j < 8; ++j) {
                int c = 32 * T + 8 * q + j;
                a[j] = f2bf(zr[(size_t)c * SPB]);
            }
            af[sg][T] = a;
        }
    }

    // stage one 16-code W tile (fp32 global -> bf16 LDS), 64B/thread
    auto stage = [&](int kt, int buf) {
        int r  = t >> 4;              // code 0..15
        int d0 = (t & 15) << 4;       // 16 d per thread
        const float* wr = w + (size_t)(kt * 16 + r) * DIM + d0;
        f32x4 v0 = *(const f32x4*)(wr);
        f32x4 v1 = *(const f32x4*)(wr + 4);
        f32x4 v2 = *(const f32x4*)(wr + 8);
        f32x4 v3 = *(const f32x4*)(wr + 12);
        bf16x8 p0, p1;
        p0[0]=f2bf(v0[0]); p0[1]=f2bf(v0[1]); p0[2]=f2bf(v0[2]); p0[3]=f2bf(v0[3]);
        p0[4]=f2bf(v1[0]); p0[5]=f2bf(v1[1]); p0[6]=f2bf(v1[2]); p0[7]=f2bf(v1[3]);
        p1[0]=f2bf(v2[0]); p1[1]=f2bf(v2[1]); p1[2]=f2bf(v2[2]); p1[3]=f2bf(v2[3]);
        p1[4]=f2bf(v3[0]); p1[5]=f2bf(v3[1]); p1[6]=f2bf(v3[2]); p1[7]=f2bf(v3[3]);
        short* dst = &wb[buf][r][d0];
        *(bf16x8*)dst       = p0;
        *(bf16x8*)(dst + 8) = p1;
    };

    float best[2][4];
    int   bidx[2][4];
#pragma unroll
    for (int sg = 0; sg < 2; ++sg)
#pragma unroll
        for (int r = 0; r < 4; ++r) { best[sg][r] = 3.4e38f; bidx[sg][r] = 0; }

    stage(0, 0);
    __syncthreads();

#pragma unroll 2
    for (int kt = 0; kt < 64; ++kt) {
        if (kt != 63) stage(kt + 1, (kt + 1) & 1);

        f32x4 acc0 = {0.f, 0.f, 0.f, 0.f};
        f32x4 acc1 = {0.f, 0.f, 0.f, 0.f};
        const short (*wbuf)[264] = wb[kt & 1];
#pragma unroll
        for (int T = 0; T < 8; ++T) {
            bf16x8 b = *(const bf16x8*)&wbuf[n][32 * T + 8 * q];
            acc0 = __builtin_amdgcn_mfma_f32_16x16x32_bf16(af[0][T], b, acc0, 0, 0, 0);
            acc1 = __builtin_amdgcn_mfma_f32_16x16x32_bf16(af[1][T], b, acc1, 0, 0, 0);
        }

        int   k   = kt * 16 + n;
        float wnv = wnl[k];
#pragma unroll
        for (int r = 0; r < 4; ++r) {
            float d0v = wnv - 2.f * acc0[r];
            if (d0v < best[0][r]) { best[0][r] = d0v; bidx[0][r] = k; }
            float d1v = wnv - 2.f * acc1[r];
            if (d1v < best[1][r]) { best[1][r] = d1v; bidx[1][r] = k; }
        }
        __syncthreads();
    }

    // ---- cross-lane argmin over the 16 columns held by lanes n=0..15 (same quad) ----
#pragma unroll
    for (int sg = 0; sg < 2; ++sg)
#pragma unroll
        for (int r = 0; r < 4; ++r) {
            float bv = best[sg][r];
            int   bi = bidx[sg][r];
#pragma unroll
            for (int m = 1; m < 16; m <<= 1) {
                float ov = __shfl_xor(bv, m);
                int   oi = __shfl_xor(bi, m);
                if (ov < bv || (ov == bv && oi < bi)) { bv = ov; bi = oi; }
            }
            if (n == 0) ridx[32 * wv + 16 * sg + 4 * q + r] = bi;
        }
    __syncthreads();

    // ---- epilogue: gather z_q, write coalesced, fused loss ----
    float lsum = 0.f;
    const float* zb2   = z   + (size_t)batch * DIM * SPB + sbase;
    float*       obase = out + (size_t)batch * DIM * SPB + sbase;
    const int f  = t & 31;    // float4 index over 128 s
    const int cg = t >> 5;    // 8 c-groups
#pragma unroll 1
    for (int i = 0; i < 32; ++i) {
        int c = cg + 8 * i;
        f32x4 zv = *(const f32x4*)(zb2 + (size_t)c * SPB + 4 * f);
        int k0 = ridx[4 * f + 0], k1 = ridx[4 * f + 1];
        int k2 = ridx[4 * f + 2], k3 = ridx[4 * f + 3];
        f32x4 qv;
        qv[0] = w[(size_t)k0 * DIM + c];
        qv[1] = w[(size_t)k1 * DIM + c];
        qv[2] = w[(size_t)k2 * DIM + c];
        qv[3] = w[(size_t)k3 * DIM + c];
        *(f32x4*)(obase + (size_t)c * SPB + 4 * f) = qv;
        f32x4 d = zv - qv;
        lsum += d[0] * d[0] + d[1] * d[1] + d[2] * d[2] + d[3] * d[3];
    }

#pragma unroll
    for (int off = 32; off; off >>= 1) lsum += __shfl_down(lsum, off);
    if (l == 0) wsum[wv] = lsum;
    __syncthreads();
    if (t == 0) atomicAdd(acc, wsum[0] + wsum[1] + wsum[2] + wsum[3]);
}

// K3: finalize the two (identical) loss scalars.
__global__ __launch_bounds__(64) void finalize(const float* __restrict__ acc,
                                               float* __restrict__ out) {
    if (threadIdx.x == 0) {
        float v = *acc * (1.f / 8388608.f);
        out[ZQ_ELEMS]     = v;
        out[ZQ_ELEMS + 1] = v;
    }
}

extern "C" void kernel_launch(void* const* d_in, const int* in_sizes, int n_in,
                              void* d_out, int out_size, void* d_ws, size_t ws_size,
                              hipStream_t stream) {
    const float* z = (const float*)d_in[0];
    const float* w = (const float*)d_in[1];
    float* out = (float*)d_out;
    float* wn  = (float*)d_ws;         // 1024 floats
    float* acc = wn + NCODES;          // 1 float

    wnorm_kernel<<<NCODES, 64, 0, stream>>>(w, wn, acc);
    vq_main<<<256, 256, 0, stream>>>(z, w, wn, out, acc);
    finalize<<<1, 64, 0, stream>>>(acc, out);
}

// Round 2
// 151.152 us; speedup vs baseline: 1.0624x; 1.0624x over previous
//
#include <hip/hip_runtime.h>
#include <hip/hip_bf16.h>

// VQ-VAE vector quantizer, MI355X gfx950.
// z_e: (32, 256, 32, 32) fp32 -> N=32768 rows, D=256 ; W: (1024, 256) fp32.
// out: z_q fp32 [8388608] ++ embedding_loss ++ commitment_loss (identical scalars).
//
// argmin_k(||w_k||^2 - 2 z.w_k) via bf16 MFMA 16x16x32.
// prep: W -> bf16 (ws) + ||w_k||^2, so the K-loop stages via async
// global_load_lds (width 16) with zero conversion VALU. Chunked LDS layout
// [s][T][q][code] satisfies the wave-uniform-base+lane*16 DMA constraint and
// makes ds_read_b128 perfectly sequential (0 bank conflicts).

#define DIM      256
#define NCODES   1024
#define SPB      1024
#define ZQ_ELEMS 8388608
#define BLK_ROWS 64
#define NBLK     512        // 32768 / 64
#define KT       32         // codes per k-tile
#define NKT      32         // 1024 / 32
#define TILE_SHORTS 8192    // 32 codes * 256 d

typedef float f32x4  __attribute__((ext_vector_type(4)));
typedef short bf16x8 __attribute__((ext_vector_type(8)));
typedef short bf16x4 __attribute__((ext_vector_type(4)));

__device__ __forceinline__ short f2bf(float f) {
    union { float f; unsigned u; } v; v.f = f;
    unsigned r = v.u + 0x7FFFu + ((v.u >> 16) & 1u);   // RNE
    return (short)(r >> 16);
}

#define GLL16(g, l)                                                            \
    __builtin_amdgcn_global_load_lds(                                          \
        (const __attribute__((address_space(1))) void*)(g),                    \
        (__attribute__((address_space(3))) void*)(l), 16, 0, 0)

// K1: W fp32 -> bf16 ws copy, wnorm, zero accumulators. 256 blocks x 256 thr.
__global__ __launch_bounds__(256) void prep(const float* __restrict__ w,
                                            short* __restrict__ wbf,
                                            float* __restrict__ wn,
                                            float* __restrict__ acc,
                                            unsigned* __restrict__ done) {
    const int t = threadIdx.x, wv = t >> 6, l = t & 63;
    const int k = blockIdx.x * 4 + wv;          // one wave per code
    const float* wr = w + (size_t)k * DIM + 4 * l;
    f32x4 v = *(const f32x4*)wr;
    bf16x4 p;
    p[0] = f2bf(v[0]); p[1] = f2bf(v[1]); p[2] = f2bf(v[2]); p[3] = f2bf(v[3]);
    *(bf16x4*)(wbf + (size_t)k * DIM + 4 * l) = p;
    float s = v[0]*v[0] + v[1]*v[1] + v[2]*v[2] + v[3]*v[3];
#pragma unroll
    for (int off = 32; off; off >>= 1) s += __shfl_down(s, off);
    if (l == 0) wn[k] = s;
    if (blockIdx.x == 0 && t == 0) { *acc = 0.f; *done = 0u; }
}

// K2: main fused kernel. grid 512 x 256 threads, 64 rows/block, 16 rows/wave.
__global__ __launch_bounds__(256) void vq_main(const float* __restrict__ z,
                                               const float* __restrict__ w,
                                               const short* __restrict__ wbf,
                                               const float* __restrict__ wn,
                                               float* __restrict__ out,
                                               float* __restrict__ acc,
                                               unsigned* __restrict__ done) {
    __shared__ __align__(16) short wb[2][TILE_SHORTS];   // 2 x 16 KB
    __shared__ float wnl[NCODES];
    __shared__ int   ridx[BLK_ROWS];
    __shared__ float wsum[4];

    const int t  = threadIdx.x;
    const int wv = t >> 6;
    const int l  = t & 63;
    const int n  = l & 15;     // code-in-subtile / A z-row lane
    const int q  = l >> 4;     // quad

    const int n0    = blockIdx.x * BLK_ROWS;
    const int batch = n0 >> 10;
    const int sbase = n0 & 1023;
    const float* zb = z + (size_t)batch * DIM * SPB + sbase;

    // per-thread staging source offsets (elements), 4 issues of 16 B each.
    // linear L = i*256 + t ; LDS byte off = L*16 ; chunk ch = L>>4, slot = L&15
    // ch = s*32 + T*4 + q  ->  src = (s*16 + slot)*DIM + 32*T + 8*q
    int soff[4];
#pragma unroll
    for (int i = 0; i < 4; ++i) {
        int L  = i * 256 + t;
        int sl = L & 15, ch = L >> 4;
        int qq = ch & 3, TT = (ch >> 2) & 7, ss = ch >> 5;
        soff[i] = (ss * 16 + sl) * DIM + 32 * TT + 8 * qq;
    }

    // kick off tile 0 (async) before the heavy A-fragment load
#pragma unroll
    for (int i = 0; i < 4; ++i)
        GLL16(wbf + soff[i], &wb[0][(i * 256 + wv * 64) * 8]);

    for (int i = t; i < NCODES; i += 256) wnl[i] = wn[i];

    // ---- A fragments: 16 z-rows per wave, all 256 d, bf16 in regs ----
    bf16x8 af[8];
    {
        const float* zr = zb + 16 * wv + n;
#pragma unroll
        for (int T = 0; T < 8; ++T) {
            bf16x8 a;
#pragma unroll
            for (int j = 0; j < 8; ++j)
                a[j] = f2bf(zr[(size_t)(32 * T + 8 * q + j) * SPB]);
            af[T] = a;
        }
    }

    float best[4];
    int   bidx[4];
#pragma unroll
    for (int r = 0; r < 4; ++r) { best[r] = 3.4e38f; bidx[r] = 0; }

    __syncthreads();

    for (int kt = 0; kt < NKT; ++kt) {
        const int buf = kt & 1;
        if (kt != NKT - 1) {
            const short* gb = wbf + (size_t)(kt + 1) * KT * DIM;
#pragma unroll
            for (int i = 0; i < 4; ++i)
                GLL16(gb + soff[i], &wb[buf ^ 1][(i * 256 + wv * 64) * 8]);
        }

        f32x4 a0 = {0.f, 0.f, 0.f, 0.f};
        f32x4 a1 = {0.f, 0.f, 0.f, 0.f};
        const short* wp = wb[buf];
#pragma unroll
        for (int T = 0; T < 8; ++T) {
            bf16x8 b0 = *(const bf16x8*)&wp[((0 * 8 + T) * 4 + q) * 128 + n * 8];
            bf16x8 b1 = *(const bf16x8*)&wp[((1 * 8 + T) * 4 + q) * 128 + n * 8];
            a0 = __builtin_amdgcn_mfma_f32_16x16x32_bf16(af[T], b0, a0, 0, 0, 0);
            a1 = __builtin_amdgcn_mfma_f32_16x16x32_bf16(af[T], b1, a1, 0, 0, 0);
        }

        const int k0 = kt * KT + n, k1 = k0 + 16;
        const float w0 = wnl[k0], w1 = wnl[k1];
#pragma unroll
        for (int r = 0; r < 4; ++r) {
            float d0 = w0 - 2.f * a0[r];
            if (d0 < best[r]) { best[r] = d0; bidx[r] = k0; }
            float d1 = w1 - 2.f * a1[r];
            if (d1 < best[r]) { best[r] = d1; bidx[r] = k1; }
        }
        __syncthreads();
    }

    // ---- cross-lane argmin over 16 code-lanes (low-index tie-break) ----
#pragma unroll
    for (int r = 0; r < 4; ++r) {
        float bv = best[r];
        int   bi = bidx[r];
#pragma unroll
        for (int m = 1; m < 16; m <<= 1) {
            float ov = __shfl_xor(bv, m);
            int   oi = __shfl_xor(bi, m);
            if (ov < bv || (ov == bv && oi < bi)) { bv = ov; bi = oi; }
        }
        if (n == 0) ridx[16 * wv + 4 * q + r] = bi;
    }
    __syncthreads();

    // ---- epilogue: gather z_q (fp32), coalesced write, fused loss ----
    float lsum = 0.f;
    float* ob = out + (size_t)batch * DIM * SPB + sbase;
    const int f  = t & 15;    // float4 index over 64 spatial
    const int cg = t >> 4;    // 16 channel groups
    const int k0 = ridx[4 * f + 0], k1 = ridx[4 * f + 1];
    const int k2 = ridx[4 * f + 2], k3 = ridx[4 * f + 3];
#pragma unroll 1
    for (int i = 0; i < 16; ++i) {
        int c = cg + 16 * i;
        f32x4 zv = *(const f32x4*)(zb + (size_t)c * SPB + 4 * f);
        f32x4 qv;
        qv[0] = w[(size_t)k0 * DIM + c];
        qv[1] = w[(size_t)k1 * DIM + c];
        qv[2] = w[(size_t)k2 * DIM + c];
        qv[3] = w[(size_t)k3 * DIM + c];
        *(f32x4*)(ob + (size_t)c * SPB + 4 * f) = qv;
        f32x4 d = zv - qv;
        lsum += d[0]*d[0] + d[1]*d[1] + d[2]*d[2] + d[3]*d[3];
    }

#pragma unroll
    for (int off = 32; off; off >>= 1) lsum += __shfl_down(lsum, off);
    if (l == 0) wsum[wv] = lsum;
    __syncthreads();
    if (t == 0) {
        atomicAdd(acc, wsum[0] + wsum[1] + wsum[2] + wsum[3]);
        __threadfence();
        unsigned prev = atomicAdd(done, 1u);
        if (prev == NBLK - 1) {                 // last block finalizes scalars
            float v = atomicAdd(acc, 0.f) * (1.f / 8388608.f);
            out[ZQ_ELEMS]     = v;
            out[ZQ_ELEMS + 1] = v;
        }
    }
}

extern "C" void kernel_launch(void* const* d_in, const int* in_sizes, int n_in,
                              void* d_out, int out_size, void* d_ws, size_t ws_size,
                              hipStream_t stream) {
    const float* z = (const float*)d_in[0];
    const float* w = (const float*)d_in[1];
    float* out = (float*)d_out;

    short*    wbf  = (short*)d_ws;                       // 1024*256 bf16 = 512 KB
    float*    wn   = (float*)(wbf + NCODES * DIM);       // 4 KB
    float*    acc  = wn + NCODES;
    unsigned* done = (unsigned*)(acc + 1);

    prep<<<256, 256, 0, stream>>>(w, wbf, wn, acc, done);
    vq_main<<<NBLK, 256, 0, stream>>>(z, w, wbf, wn, out, acc, done);
}

// Round 3
// 149.425 us; speedup vs baseline: 1.0747x; 1.0116x over previous
//
#include <hip/hip_runtime.h>
#include <hip/hip_bf16.h>

// VQ-VAE vector quantizer, MI355X gfx950 — round 3.
// z_e: (32, 256, 32, 32) fp32 -> N=32768 rows, D=256 ; W: (1024, 256) fp32.
// out: z_q fp32 [8388608] ++ embedding_loss ++ commitment_loss (identical scalars).
//
// Design: 1-wave blocks (64 thr), 64 z-rows/wave in registers (4 MFMA row-sets,
// 128 VGPRs of A), KT=64-code W tiles double-buffered in LDS via contiguous
// global_load_lds with granule-XOR swizzle (conflict-free b128 frag reads,
// ~8 cache-line requests per staging instr). No inter-wave sync; 2 independent
// blocks/CU hide each other's latency. Epilogue: per-row 1KB DMA gather of the
// selected codes (rotate-swizzled), LDS transpose, coalesced float4 writes +
// fused loss.

#define DIM      256
#define NCODES   1024
#define SPB      1024
#define ZQ_ELEMS 8388608
#define NBLK     512       // 32768 rows / 64
#define KT       64        // codes per k-tile
#define NKT      16        // 1024 / 64

typedef float f32x4  __attribute__((ext_vector_type(4)));
typedef short bf16x8 __attribute__((ext_vector_type(8)));
typedef short bf16x4 __attribute__((ext_vector_type(4)));

__device__ __forceinline__ short f2bf(float f) {
    union { float f; unsigned u; } v; v.f = f;
    unsigned r = v.u + 0x7FFFu + ((v.u >> 16) & 1u);   // RNE
    return (short)(r >> 16);
}

#define GLL16(g, l)                                                            \
    __builtin_amdgcn_global_load_lds(                                          \
        (const __attribute__((address_space(1))) void*)(g),                    \
        (__attribute__((address_space(3))) void*)(l), 16, 0, 0)

// K1: W fp32 -> bf16 ws copy (row-major), wnorm, zero accumulators.
__global__ __launch_bounds__(256) void prep(const float* __restrict__ w,
                                            short* __restrict__ wbf,
                                            float* __restrict__ wn,
                                            float* __restrict__ acc,
                                            unsigned* __restrict__ done) {
    const int t = threadIdx.x, wv = t >> 6, l = t & 63;
    const int k = blockIdx.x * 4 + wv;          // one wave per code
    const float* wr = w + (size_t)k * DIM + 4 * l;
    f32x4 v = *(const f32x4*)wr;
    bf16x4 p;
    p[0] = f2bf(v[0]); p[1] = f2bf(v[1]); p[2] = f2bf(v[2]); p[3] = f2bf(v[3]);
    *(bf16x4*)(wbf + (size_t)k * DIM + 4 * l) = p;
    float s = v[0]*v[0] + v[1]*v[1] + v[2]*v[2] + v[3]*v[3];
#pragma unroll
    for (int off = 32; off; off >>= 1) s += __shfl_down(s, off);
    if (l == 0) wn[k] = s;
    if (blockIdx.x == 0 && t == 0) { *acc = 0.f; *done = 0u; }
}

// K2: main kernel. grid 512 x 64 threads (1 wave), 64 rows/block.
__global__ __launch_bounds__(64, 1) void vq_main(const float* __restrict__ z,
                                                 const float* __restrict__ w,
                                                 const short* __restrict__ wbf,
                                                 const float* __restrict__ wn,
                                                 float* __restrict__ out,
                                                 float* __restrict__ acc,
                                                 unsigned* __restrict__ done) {
    // smem map: [0,65536) = W-tile dbuf (2 x 32 KB)  UNION  zql 64x256 f32
    //           [65536,69632) = wnl (1024 f32), [69632,69888) = ridx (64 int)
    __shared__ __align__(16) char smem[69888];
    float* zql  = (float*)smem;
    float* wnl  = (float*)(smem + 65536);
    int*   ridx = (int*)(smem + 69632);

    const int l   = threadIdx.x;
    const int n16 = l & 15;       // code lane within 16-group / A row lane
    const int q   = l >> 4;       // quad

    const int n0    = blockIdx.x * 64;
    const int batch = n0 >> 10;
    const int sbase = n0 & 1023;
    const float* zb = z + (size_t)batch * DIM * SPB + sbase;

    // ---- staging source offsets (elements within one 64x256 tile) ----
    // LDS granule G = i*64 + l ; row n = G>>5 ; phys granule p = G&31 = l&31
    // source logical granule = p ^ (n&7)  (XOR within 128-B windows -> same
    // cache lines as contiguous; read-side frag addresses use the same XOR)
    int soff[32];
#pragma unroll
    for (int i = 0; i < 32; ++i) {
        int n = 2 * i + (l >> 5);
        int p = l & 31;
        soff[i] = n * 256 + 8 * (p ^ (n & 7));
    }

    // kick tile 0 (async DMA) before the heavy A-fragment load
#pragma unroll
    for (int i = 0; i < 32; ++i) GLL16(wbf + soff[i], smem + i * 1024);

    // wnorm -> LDS (coalesced f32x4)
#pragma unroll
    for (int i = 0; i < 4; ++i) {
        f32x4 v = *(const f32x4*)(wn + 4 * l + 256 * i);
        *(f32x4*)(wnl + 4 * l + 256 * i) = v;
    }

    // ---- A fragments: 64 rows (4 sets of 16), all 256 d, bf16 in regs ----
    bf16x8 af[4][8];
#pragma unroll
    for (int s = 0; s < 4; ++s) {
        const float* zr = zb + s * 16 + n16;
#pragma unroll
        for (int T = 0; T < 8; ++T) {
            bf16x8 a;
#pragma unroll
            for (int j = 0; j < 8; ++j)
                a[j] = f2bf(zr[(size_t)(32 * T + 8 * q + j) * SPB]);
            af[s][T] = a;
        }
    }

    // per-lane fragment byte offsets within a code row (XOR swizzle)
    int offT[8];
#pragma unroll
    for (int T = 0; T < 8; ++T) offT[T] = ((4 * T + q) ^ (n16 & 7)) * 16;

    float best[4][4];
    int   bidx[4][4];
#pragma unroll
    for (int s = 0; s < 4; ++s)
#pragma unroll
        for (int r = 0; r < 4; ++r) { best[s][r] = 3.4e38f; bidx[s][r] = 0; }

    __builtin_amdgcn_s_waitcnt(0x0070);   // vmcnt(0) lgkmcnt(0): tile-0 DMA landed
    __syncthreads();

    for (int kt = 0; kt < NKT; ++kt) {
        const int buf = kt & 1;
        if (kt != NKT - 1) {
            const short* gb = wbf + (size_t)(kt + 1) * KT * DIM;
            char* db = smem + (buf ^ 1) * 32768;
#pragma unroll
            for (int i = 0; i < 32; ++i) GLL16(gb + soff[i], db + i * 1024);
        }

        const char* wp = smem + buf * 32768;
        f32x4 ac[4][4];
#pragma unroll
        for (int s = 0; s < 4; ++s)
#pragma unroll
            for (int g = 0; g < 4; ++g) ac[s][g] = (f32x4){0.f, 0.f, 0.f, 0.f};

#pragma unroll
        for (int T = 0; T < 8; ++T) {
            bf16x8 bfr[4];
#pragma unroll
            for (int g = 0; g < 4; ++g)
                bfr[g] = *(const bf16x8*)(wp + (g * 16 + n16) * 512 + offT[T]);
#pragma unroll
            for (int s = 0; s < 4; ++s)
#pragma unroll
                for (int g = 0; g < 4; ++g)
                    ac[s][g] = __builtin_amdgcn_mfma_f32_16x16x32_bf16(
                        af[s][T], bfr[g], ac[s][g], 0, 0, 0);
        }

#pragma unroll
        for (int g = 0; g < 4; ++g) {
            const int   k   = kt * KT + g * 16 + n16;
            const float wnv = wnl[k];
#pragma unroll
            for (int s = 0; s < 4; ++s)
#pragma unroll
                for (int r = 0; r < 4; ++r) {
                    float d = wnv - 2.f * ac[s][g][r];
                    if (d < best[s][r]) { best[s][r] = d; bidx[s][r] = k; }
                }
        }
        __builtin_amdgcn_s_waitcnt(0x0070);   // drain next-tile DMA (issued above)
        __syncthreads();
    }

    // ---- cross-lane argmin over 16 code lanes (low-index tie-break) ----
#pragma unroll
    for (int s = 0; s < 4; ++s)
#pragma unroll
        for (int r = 0; r < 4; ++r) {
            float bv = best[s][r];
            int   bi = bidx[s][r];
#pragma unroll
            for (int m = 1; m < 16; m <<= 1) {
                float ov = __shfl_xor(bv, m);
                int   oi = __shfl_xor(bi, m);
                if (ov < bv || (ov == bv && oi < bi)) { bv = ov; bi = oi; }
            }
            if (n16 == 0) ridx[s * 16 + q * 4 + r] = bi;
        }
    __syncthreads();

    // ---- Phase A: DMA-gather selected code rows -> zql[s][*], rotated by s>>2
    int myidx = ridx[l];
    for (int s = 0; s < 64; ++s) {
        int ks = __shfl(myidx, s);
        const float* src = w + (size_t)ks * DIM + 4 * ((l - (s >> 2)) & 63);
        GLL16(src, smem + s * 1024);
    }
    __builtin_amdgcn_s_waitcnt(0x0070);
    __syncthreads();

    // ---- Phase B: transpose out of LDS, coalesced float4 writes, fused loss
    // lane (n16, q): rows s = 4*n16..4*n16+3, channels c = q + 4*j
    // logical granule j of row s sits at phys granule (j + (s>>2)) & 63 = (j+n16)&63
    float lsum = 0.f;
    float* ob = out + (size_t)batch * DIM * SPB + sbase;
#pragma unroll 4
    for (int j = 0; j < 64; ++j) {
        const int c  = q + 4 * j;
        const int pg = (j + n16) & 63;
        f32x4 qv;
#pragma unroll
        for (int r = 0; r < 4; ++r)
            qv[r] = zql[(4 * n16 + r) * 256 + 4 * pg + q];
        f32x4 zv = *(const f32x4*)(zb + (size_t)c * SPB + 4 * n16);
        *(f32x4*)(ob + (size_t)c * SPB + 4 * n16) = qv;
        f32x4 d = zv - qv;
        lsum += d[0]*d[0] + d[1]*d[1] + d[2]*d[2] + d[3]*d[3];
    }

#pragma unroll
    for (int off = 32; off; off >>= 1) lsum += __shfl_down(lsum, off);
    if (l == 0) {
        atomicAdd(acc, lsum);
        __threadfence();
        unsigned prev = atomicAdd(done, 1u);
        if (prev == NBLK - 1) {                 // last block finalizes scalars
            float v = atomicAdd(acc, 0.f) * (1.f / 8388608.f);
            out[ZQ_ELEMS]     = v;
            out[ZQ_ELEMS + 1] = v;
        }
    }
}

extern "C" void kernel_launch(void* const* d_in, const int* in_sizes, int n_in,
                              void* d_out, int out_size, void* d_ws, size_t ws_size,
                              hipStream_t stream) {
    const float* z = (const float*)d_in[0];
    const float* w = (const float*)d_in[1];
    float* out = (float*)d_out;

    short*    wbf  = (short*)d_ws;                       // 512 KB bf16 W
    float*    wn   = (float*)(wbf + NCODES * DIM);       // 4 KB
    float*    acc  = wn + NCODES;
    unsigned* done = (unsigned*)(acc + 1);

    prep<<<256, 256, 0, stream>>>(w, wbf, wn, acc, done);
    vq_main<<<NBLK, 64, 0, stream>>>(z, w, wbf, wn, out, acc, done);
}

// Round 4
// 136.694 us; speedup vs baseline: 1.1748x; 1.0931x over previous
//
#include <hip/hip_runtime.h>
#include <hip/hip_bf16.h>

// VQ-VAE vector quantizer, MI355X gfx950 — round 4: phase-split + fully
// coalesced DRAM access (>=256B contiguous per instruction everywhere).
// K1 prep:   W fp32 -> bf16 (ws) + ||w||^2 + zero accumulators
// K2 gemm:   scores argmin -> idx[32768]   (z read coalesced, LDS transpose)
// K3 gather: z_q = W[idx] write + fused MSE losses (all coalesced)

#define DIM      256
#define NCODES   1024
#define SPB      1024
#define ZQ_ELEMS 8388608
#define NBLK     512       // 32768 rows / 64

typedef float f32x4  __attribute__((ext_vector_type(4)));
typedef short bf16x8 __attribute__((ext_vector_type(8)));
typedef short bf16x4 __attribute__((ext_vector_type(4)));

__device__ __forceinline__ short f2bf(float f) {
    union { float f; unsigned u; } v; v.f = f;
    unsigned r = v.u + 0x7FFFu + ((v.u >> 16) & 1u);   // RNE
    return (short)(r >> 16);
}

#define GLL16(g, l)                                                            \
    __builtin_amdgcn_global_load_lds(                                          \
        (const __attribute__((address_space(1))) void*)(g),                    \
        (__attribute__((address_space(3))) void*)(l), 16, 0, 0)

// ---------------- K1: prep ----------------
__global__ __launch_bounds__(256) void prep(const float* __restrict__ w,
                                            short* __restrict__ wbf,
                                            float* __restrict__ wn,
                                            float* __restrict__ acc,
                                            unsigned* __restrict__ done) {
    const int t = threadIdx.x, wv = t >> 6, l = t & 63;
    const int k = blockIdx.x * 4 + wv;          // one wave per code
    const float* wr = w + (size_t)k * DIM + 4 * l;
    f32x4 v = *(const f32x4*)wr;
    bf16x4 p;
    p[0] = f2bf(v[0]); p[1] = f2bf(v[1]); p[2] = f2bf(v[2]); p[3] = f2bf(v[3]);
    *(bf16x4*)(wbf + (size_t)k * DIM + 4 * l) = p;
    float s = v[0]*v[0] + v[1]*v[1] + v[2]*v[2] + v[3]*v[3];
#pragma unroll
    for (int off = 32; off; off >>= 1) s += __shfl_down(s, off);
    if (l == 0) wn[k] = s;
    if (blockIdx.x == 0 && t == 0) { *acc = 0.f; *done = 0u; }
}

// ---------------- K2: gemm + argmin -> idx ----------------
// grid 512 x 256 (4 waves), 64 z-rows/block, 16 rows/wave.
// LDS: zs fp32 [256 c][65] (66560 B) UNION wb bf16 dbuf 2 x (32 codes x 256 d)
__global__ __launch_bounds__(256, 2) void vq_gemm(const float* __restrict__ z,
                                                  const short* __restrict__ wbf,
                                                  const float* __restrict__ wn,
                                                  int* __restrict__ idx) {
    __shared__ __align__(16) char smem[66560];
    float* zs = (float*)smem;                    // [c][s] stride 65
    short* wb = (short*)smem;                    // 2 x 16384 B tiles

    const int t   = threadIdx.x;
    const int wv  = t >> 6;
    const int l   = t & 63;
    const int n16 = l & 15;
    const int q   = l >> 4;

    const int n0    = blockIdx.x * 64;
    const int batch = n0 >> 10;
    const int sbase = n0 & 1023;
    const float* zb = z + (size_t)batch * DIM * SPB + sbase;

    // ---- A staging: coalesced f32x4 reads (256B/row-segment), LDS transpose
    {
        const int sx = t & 15;       // 16 lanes x f32x4 = 64 s
        const int c0 = t >> 4;       // 16 c-groups
#pragma unroll
        for (int g = 0; g < 4; ++g) {
            f32x4 v[4];
#pragma unroll
            for (int i = 0; i < 4; ++i) {
                int c = c0 + 16 * (4 * g + i);
                v[i] = *(const f32x4*)(zb + (size_t)c * SPB + 4 * sx);
            }
#pragma unroll
            for (int i = 0; i < 4; ++i) {
                int c = c0 + 16 * (4 * g + i);
                *(f32x4*)&zs[65 * c + 4 * sx] = v[i];
            }
        }
    }
    __syncthreads();

    // ---- A fragments: row m = n16 (block row 16*wv + n16), d = 32T+8q+j
    bf16x8 af[8];
#pragma unroll
    for (int T = 0; T < 8; ++T) {
        bf16x8 a;
#pragma unroll
        for (int j = 0; j < 8; ++j) {
            int d = 32 * T + 8 * q + j;
            a[j] = f2bf(zs[65 * d + 16 * wv + n16]);
        }
        af[T] = a;
    }
    __syncthreads();   // zs dead; wb region may now be overwritten

    // ---- B staging offsets: 32-code tile, granule-XOR swizzle
    // G = i*256 + t ; row n = G>>5 ; phys granule p = G&31 ; logical = p^(n&7)
    int soff[4];
#pragma unroll
    for (int i = 0; i < 4; ++i) {
        int G = i * 256 + t;
        int n = G >> 5, p = G & 31;
        soff[i] = n * 256 + 8 * (p ^ (n & 7));
    }
    int offT[8];
#pragma unroll
    for (int T = 0; T < 8; ++T) offT[T] = ((4 * T + q) ^ (n16 & 7)) * 16;

    // tile 0 DMA
#pragma unroll
    for (int i = 0; i < 4; ++i)
        GLL16(wbf + soff[i], smem + (i * 256 + t) * 16 - (size_t)t * 16 + (size_t)(t)*16);
    // (the expression above is just smem + G*16 with G = i*256+t)

    float best[4];
    int   bidx[4];
#pragma unroll
    for (int r = 0; r < 4; ++r) { best[r] = 3.4e38f; bidx[r] = 0; }

    __builtin_amdgcn_s_waitcnt(0x0070);
    __syncthreads();

    for (int kt = 0; kt < 32; ++kt) {
        const int buf = kt & 1;
        if (kt != 31) {
            const short* gb = wbf + (size_t)(kt + 1) * 32 * DIM;
            char* db = smem + (buf ^ 1) * 16384;
#pragma unroll
            for (int i = 0; i < 4; ++i)
                GLL16(gb + soff[i], db + (i * 256 + t) * 16);
        }
        const int k0 = kt * 32 + n16, k1 = k0 + 16;
        float wv0 = wn[k0], wv1 = wn[k1];

        const char* wp = smem + buf * 16384;
        f32x4 a0 = {0.f, 0.f, 0.f, 0.f};
        f32x4 a1 = {0.f, 0.f, 0.f, 0.f};
#pragma unroll
        for (int T = 0; T < 8; ++T) {
            bf16x8 b0 = *(const bf16x8*)(wp + (0 * 16 + n16) * 512 + offT[T]);
            bf16x8 b1 = *(const bf16x8*)(wp + (1 * 16 + n16) * 512 + offT[T]);
            a0 = __builtin_amdgcn_mfma_f32_16x16x32_bf16(af[T], b0, a0, 0, 0, 0);
            a1 = __builtin_amdgcn_mfma_f32_16x16x32_bf16(af[T], b1, a1, 0, 0, 0);
        }
#pragma unroll
        for (int r = 0; r < 4; ++r) {
            float d0 = wv0 - 2.f * a0[r];
            if (d0 < best[r]) { best[r] = d0; bidx[r] = k0; }
            float d1 = wv1 - 2.f * a1[r];
            if (d1 < best[r]) { best[r] = d1; bidx[r] = k1; }
        }
        __builtin_amdgcn_s_waitcnt(0x0070);
        __syncthreads();
    }

    // ---- cross-lane argmin over 16 code lanes; C row m = 4q+r
#pragma unroll
    for (int r = 0; r < 4; ++r) {
        float bv = best[r];
        int   bi = bidx[r];
#pragma unroll
        for (int m = 1; m < 16; m <<= 1) {
            float ov = __shfl_xor(bv, m);
            int   oi = __shfl_xor(bi, m);
            if (ov < bv || (ov == bv && oi < bi)) { bv = ov; bi = oi; }
        }
        if (n16 == 0) idx[n0 + 16 * wv + 4 * q + r] = bi;
    }
}

// ---------------- K3: gather + write + loss ----------------
// grid 512 x 256, 64 positions/block. zql: 64 rows x 256 f32, row s rotated
// by s granules (16B) so the transposed read is conflict-free.
__global__ __launch_bounds__(256, 2) void vq_gather(const float* __restrict__ z,
                                                    const float* __restrict__ w,
                                                    const int* __restrict__ idx,
                                                    float* __restrict__ out,
                                                    float* __restrict__ acc,
                                                    unsigned* __restrict__ done) {
    __shared__ __align__(16) float zql[64 * 256];
    __shared__ float wsum[4];

    const int t  = threadIdx.x;
    const int wv = t >> 6;
    const int l  = t & 63;

    const int n0    = blockIdx.x * 64;
    const int batch = n0 >> 10;
    const int sbase = n0 & 1023;
    const float* zb = z   + (size_t)batch * DIM * SPB + sbase;
    float*       ob = out + (size_t)batch * DIM * SPB + sbase;

    // DMA-gather selected code rows (1 KB each), rotated by s granules
    for (int s = 16 * wv; s < 16 * wv + 16; ++s) {
        int ks = idx[n0 + s];
        const float* src = w + (size_t)ks * DIM + 4 * ((l - s) & 63);
        GLL16(src, (char*)zql + s * 1024 + l * 16);
    }
    __builtin_amdgcn_s_waitcnt(0x0070);
    __syncthreads();

    // transposed read: w_row[s][c] at phys dword (c + 4s) & 255
    const int x  = t & 15;     // s-group: s = 4x + r
    const int cg = t >> 4;     // 16 channel groups
    float lsum = 0.f;
#pragma unroll 4
    for (int i = 0; i < 16; ++i) {
        int c = cg + 16 * i;
        f32x4 qv;
#pragma unroll
        for (int r = 0; r < 4; ++r) {
            int s = 4 * x + r;
            qv[r] = zql[s * 256 + ((c + 4 * s) & 255)];
        }
        f32x4 zv = *(const f32x4*)(zb + (size_t)c * SPB + 4 * x);
        *(f32x4*)(ob + (size_t)c * SPB + 4 * x) = qv;
        f32x4 d = zv - qv;
        lsum += d[0]*d[0] + d[1]*d[1] + d[2]*d[2] + d[3]*d[3];
    }

#pragma unroll
    for (int off = 32; off; off >>= 1) lsum += __shfl_down(lsum, off);
    if (l == 0) wsum[wv] = lsum;
    __syncthreads();
    if (t == 0) {
        atomicAdd(acc, wsum[0] + wsum[1] + wsum[2] + wsum[3]);
        __threadfence();
        unsigned prev = atomicAdd(done, 1u);
        if (prev == NBLK - 1) {
            float v = atomicAdd(acc, 0.f) * (1.f / 8388608.f);
            out[ZQ_ELEMS]     = v;
            out[ZQ_ELEMS + 1] = v;
        }
    }
}

extern "C" void kernel_launch(void* const* d_in, const int* in_sizes, int n_in,
                              void* d_out, int out_size, void* d_ws, size_t ws_size,
                              hipStream_t stream) {
    const float* z = (const float*)d_in[0];
    const float* w = (const float*)d_in[1];
    float* out = (float*)d_out;

    char* ws = (char*)d_ws;
    short*    wbf  = (short*)ws;                   // 512 KB
    float*    wn   = (float*)(ws + 524288);        // 4 KB
    float*    acc  = (float*)(ws + 528384);
    unsigned* done = (unsigned*)(ws + 528388);
    int*      idx  = (int*)(ws + 532480);          // 128 KB

    prep<<<256, 256, 0, stream>>>(w, wbf, wn, acc, done);
    vq_gemm<<<NBLK, 256, 0, stream>>>(z, wbf, wn, idx);
    vq_gather<<<NBLK, 256, 0, stream>>>(z, w, idx, out, acc, done);
}